// Round 9
// baseline (841.934 us; speedup 1.0000x reference)
//
#include <hip/hip_runtime.h>

#define TT 128
#define NB 64
#define NSZ 32
#define MSZ 8
#define PSZ 16

typedef __attribute__((ext_vector_type(8)))  short bf16x8;
typedef __attribute__((ext_vector_type(16))) float f32x16;
typedef __attribute__((ext_vector_type(4)))  float f32x4;
typedef __attribute__((ext_vector_type(4)))  unsigned int uint4v;
typedef __attribute__((ext_vector_type(2)))  unsigned int uint2v;

union U8 { uint4v u; bf16x8 b; };

__device__ __forceinline__ float frcp(float x){ return __builtin_amdgcn_rcpf(x); }
__device__ __forceinline__ float rdl(float x, int lane){
  return __int_as_float(__builtin_amdgcn_readlane(__float_as_int(x), lane));
}

// bf16 split helpers: hi = truncated top-16 of f32; lo = bf16(x - f32(hi)).
__device__ __forceinline__ unsigned int hipack(float x0, float x1){
  return __builtin_amdgcn_perm(__float_as_uint(x1), __float_as_uint(x0), 0x07060302u);
}
__device__ __forceinline__ unsigned int lopack(float x0, float x1){
  float l0 = x0 - __uint_as_float(__float_as_uint(x0) & 0xFFFF0000u);
  float l1 = x1 - __uint_as_float(__float_as_uint(x1) & 0xFFFF0000u);
  return __builtin_amdgcn_perm(__float_as_uint(l1), __float_as_uint(l0), 0x07060302u);
}
__device__ __forceinline__ unsigned int packhl(float x){
  unsigned int u = __float_as_uint(x);
  unsigned int h = u & 0xFFFF0000u;
  float xl = x - __uint_as_float(h);
  return h | (__float_as_uint(xl) >> 16);
}
__device__ __forceinline__ float unpk(unsigned int u){
  return __uint_as_float(u & 0xFFFF0000u) + __uint_as_float(u << 16);
}
__device__ __forceinline__ uint4v frag_hi(uint4v a, uint4v b){
  uint4v r;
  r.x = __builtin_amdgcn_perm(a.y, a.x, 0x07060302u);
  r.y = __builtin_amdgcn_perm(a.w, a.z, 0x07060302u);
  r.z = __builtin_amdgcn_perm(b.y, b.x, 0x07060302u);
  r.w = __builtin_amdgcn_perm(b.w, b.z, 0x07060302u);
  return r;
}
__device__ __forceinline__ uint4v frag_lo(uint4v a, uint4v b){
  uint4v r;
  r.x = __builtin_amdgcn_perm(a.y, a.x, 0x05040100u);
  r.y = __builtin_amdgcn_perm(a.w, a.z, 0x05040100u);
  r.z = __builtin_amdgcn_perm(b.y, b.x, 0x05040100u);
  r.w = __builtin_amdgcn_perm(b.w, b.z, 0x05040100u);
  return r;
}
__device__ __forceinline__ float blof(unsigned int h, unsigned int l){
  return __uint_as_float(h << 16) + __uint_as_float(l << 16);
}
__device__ __forceinline__ float bhif(unsigned int h, unsigned int l){
  return __uint_as_float(h & 0xFFFF0000u) + __uint_as_float(l & 0xFFFF0000u);
}
__device__ __forceinline__ f32x16 mfma32(bf16x8 a, bf16x8 b, f32x16 c){
  return __builtin_amdgcn_mfma_f32_32x32x16_bf16(a, b, c, 0, 0, 0);
}
__device__ __forceinline__ f32x4 mfma16(bf16x8 a, bf16x8 b, f32x4 c){
  return __builtin_amdgcn_mfma_f32_16x16x32_bf16(a, b, c, 0, 0, 0);
}
__device__ __forceinline__ void split16(float4 v0, float4 v1, float4 v2, float4 v3,
                                        unsigned short* hi, unsigned short* lo){
  uint4v hw0, hw1, lw0, lw1;
  hw0.x=hipack(v0.x,v0.y); hw0.y=hipack(v0.z,v0.w); hw0.z=hipack(v1.x,v1.y); hw0.w=hipack(v1.z,v1.w);
  hw1.x=hipack(v2.x,v2.y); hw1.y=hipack(v2.z,v2.w); hw1.z=hipack(v3.x,v3.y); hw1.w=hipack(v3.z,v3.w);
  lw0.x=lopack(v0.x,v0.y); lw0.y=lopack(v0.z,v0.w); lw0.z=lopack(v1.x,v1.y); lw0.w=lopack(v1.z,v1.w);
  lw1.x=lopack(v2.x,v2.y); lw1.y=lopack(v2.z,v2.w); lw1.z=lopack(v3.x,v3.y); lw1.w=lopack(v3.z,v3.w);
  *(uint4v*)hi = hw0; *(uint4v*)(hi+8) = hw1;
  *(uint4v*)lo = lw0; *(uint4v*)(lo+8) = lw1;
}
__device__ __forceinline__ void split8(float4 v0, float4 v1,
                                       unsigned short* hi, unsigned short* lo){
  uint4v hw, lw;
  hw.x=hipack(v0.x,v0.y); hw.y=hipack(v0.z,v0.w); hw.z=hipack(v1.x,v1.y); hw.w=hipack(v1.z,v1.w);
  lw.x=lopack(v0.x,v0.y); lw.y=lopack(v0.z,v0.w); lw.z=lopack(v1.x,v1.y); lw.w=lopack(v1.z,v1.w);
  *(uint4v*)hi = hw; *(uint4v*)lo = lw;
}
// pack 8 f32 (from float4 pair) into hi/lo bf16x8 fragments
#define MK8(v0, v1, HI, LO) do { \
  (HI).u.x = hipack((v0).x,(v0).y); (HI).u.y = hipack((v0).z,(v0).w); \
  (HI).u.z = hipack((v1).x,(v1).y); (HI).u.w = hipack((v1).z,(v1).w); \
  (LO).u.x = lopack((v0).x,(v0).y); (LO).u.y = lopack((v0).z,(v0).w); \
  (LO).u.z = lopack((v1).x,(v1).y); (LO).u.w = lopack((v1).z,(v1).w); \
} while(0)

// Build B-fragments (sets 0 and 1) from a 32x32 D-layout register file `uu`
// using a cross-half shfl: lane (c32,h) reg r holds M[(r&3)+8*(r>>2)+4*h][c32].
// Output: B[k][c32] fragments, set0 k=0..15, set1 k=16..31, split hi/lo.
#define DLAYOUT_TO_BFRAG(uu, h, B_H0, B_L0, B_H1, B_L1) do { \
  float sw_[16]; \
  _Pragma("unroll") \
  for (int r_=0;r_<16;++r_) sw_[r_] = __shfl_xor((uu)[r_], 32); \
  float v0_[8], v1_[8]; \
  v0_[0]=(h)? sw_[4] :(uu)[0];  v0_[1]=(h)? sw_[5] :(uu)[1]; \
  v0_[2]=(h)? sw_[6] :(uu)[2];  v0_[3]=(h)? sw_[7] :(uu)[3]; \
  v0_[4]=(h)? (uu)[4]:sw_[0];   v0_[5]=(h)? (uu)[5]:sw_[1]; \
  v0_[6]=(h)? (uu)[6]:sw_[2];   v0_[7]=(h)? (uu)[7]:sw_[3]; \
  v1_[0]=(h)? sw_[12]:(uu)[8];  v1_[1]=(h)? sw_[13]:(uu)[9]; \
  v1_[2]=(h)? sw_[14]:(uu)[10]; v1_[3]=(h)? sw_[15]:(uu)[11]; \
  v1_[4]=(h)? (uu)[12]:sw_[8];  v1_[5]=(h)? (uu)[13]:sw_[9]; \
  v1_[6]=(h)? (uu)[14]:sw_[10]; v1_[7]=(h)? (uu)[15]:sw_[11]; \
  (B_H0).u.x=hipack(v0_[0],v0_[1]); (B_H0).u.y=hipack(v0_[2],v0_[3]); \
  (B_H0).u.z=hipack(v0_[4],v0_[5]); (B_H0).u.w=hipack(v0_[6],v0_[7]); \
  (B_L0).u.x=lopack(v0_[0],v0_[1]); (B_L0).u.y=lopack(v0_[2],v0_[3]); \
  (B_L0).u.z=lopack(v0_[4],v0_[5]); (B_L0).u.w=lopack(v0_[6],v0_[7]); \
  (B_H1).u.x=hipack(v1_[0],v1_[1]); (B_H1).u.y=hipack(v1_[2],v1_[3]); \
  (B_H1).u.z=hipack(v1_[4],v1_[5]); (B_H1).u.w=hipack(v1_[6],v1_[7]); \
  (B_L1).u.x=lopack(v1_[0],v1_[1]); (B_L1).u.y=lopack(v1_[2],v1_[3]); \
  (B_L1).u.z=lopack(v1_[4],v1_[5]); (B_L1).u.w=lopack(v1_[6],v1_[7]); \
} while(0)

// ===== Forward Kalman filter: 1 wave/batch, MFMA bf16-split matmuls (unchanged R8) =====
__global__ __launch_bounds__(64) void kf_forward(
    const float* __restrict__ Yg, const float* __restrict__ Ug,
    const float* __restrict__ Ag, const float* __restrict__ Bg,
    const float* __restrict__ Cg, const float* __restrict__ mu0g,
    const float* __restrict__ Sig0g,
    float* __restrict__ outg, float* __restrict__ wsSig, float* __restrict__ wsMu)
{
  const int l   = threadIdx.x;
  const int b   = blockIdx.x;
  const int c32 = l & 31;
  const int h   = l >> 5;
  const int c16 = l & 15;
  const int q4  = l >> 4;
  const int kofA = h * 8;
  const int kofC = q4 * 8;
  const int rA = l >> 1, cA = (l & 1) << 4;
  const int rC = l >> 2, cC = (l & 3) << 3;

  __shared__ __align__(16) unsigned short Ahi[32][40], Alo[32][40];
  __shared__ __align__(16) unsigned short Chi[16][40], Clo[16][40];
  __shared__ __align__(16) unsigned short Ghi[32][40], Glo[32][40];
  __shared__ __align__(16) unsigned short Phi[32][40], Plo[32][40];
  __shared__ __align__(16) unsigned short Yhi[32][24], Ylo[32][24];
  __shared__ __align__(16) unsigned int   ZP[16][40];
  __shared__ __align__(16) unsigned int   KtTP[32][26];
  __shared__ __align__(16) float SLf[16][20];
  __shared__ __align__(16) float CSf[16][40];
  __shared__ __align__(16) float Bm[32][12];
  __shared__ __align__(16) float muf[32], mupf[32], rvf[16], yvf[16], uvf[8];

  const size_t bt0 = (size_t)b * TT;

  {
    const float* ap = Ag + bt0*1024 + rA*32 + cA;
    split16(*(const float4*)(ap+0), *(const float4*)(ap+4),
            *(const float4*)(ap+8), *(const float4*)(ap+12),
            &Ahi[rA][cA], &Alo[rA][cA]);
    const float* sp0 = Sig0g + rA*32 + cA;
    split16(*(const float4*)(sp0+0), *(const float4*)(sp0+4),
            *(const float4*)(sp0+8), *(const float4*)(sp0+12),
            &Ghi[rA][cA], &Glo[rA][cA]);
    const float* cp = Cg + bt0*512 + rC*32 + cC;
    split8(*(const float4*)(cp+0), *(const float4*)(cp+4),
           &Chi[rC][cC], &Clo[rC][cC]);
    *(float4*)&Bm[l>>1][(l&1)*4] = *(const float4*)(Bg + bt0*256 + (l>>1)*8 + (l&1)*4);
    if (l < 32) muf[l] = mu0g[l];
    if (l < 16) yvf[l] = Yg[bt0*16 + l];
    if (l < 8)  uvf[l] = Ug[bt0*8 + l];
  }

  for (int t = 0; t < TT; ++t) {
    const size_t bt = bt0 + t;

    // ---- P1': U = Sigma * A^T  (D-layout kept in registers) ----
    U8 a_h0, a_h1, a_l0, a_l1, s_h0, s_h1, s_l0, s_l1;
    a_h0.u = *(const uint4v*)&Ahi[c32][0  + kofA];
    a_h1.u = *(const uint4v*)&Ahi[c32][16 + kofA];
    a_l0.u = *(const uint4v*)&Alo[c32][0  + kofA];
    a_l1.u = *(const uint4v*)&Alo[c32][16 + kofA];
    s_h0.u = *(const uint4v*)&Ghi[c32][0  + kofA];
    s_h1.u = *(const uint4v*)&Ghi[c32][16 + kofA];
    s_l0.u = *(const uint4v*)&Glo[c32][0  + kofA];
    s_l1.u = *(const uint4v*)&Glo[c32][16 + kofA];
    f32x16 t1a, t1b;
    #pragma unroll
    for (int r=0;r<16;++r){ t1a[r] = 0.f; t1b[r] = 0.f; }
    t1a = mfma32(s_h0.b, a_h0.b, t1a);
    t1a = mfma32(s_h0.b, a_l0.b, t1a);
    t1a = mfma32(s_l0.b, a_h0.b, t1a);
    t1b = mfma32(s_h1.b, a_h1.b, t1b);
    t1b = mfma32(s_h1.b, a_l1.b, t1b);
    t1b = mfma32(s_l1.b, a_h1.b, t1b);
    float uu[16];
    #pragma unroll
    for (int r=0;r<16;++r) uu[r] = t1a[r] + t1b[r];
    // mu_p = A*mu + B*u
    float part = 0.f;
    {
      float4 m0 = *(const float4*)&muf[kofA];
      float4 m1 = *(const float4*)&muf[kofA+4];
      float4 m2 = *(const float4*)&muf[16+kofA];
      float4 m3 = *(const float4*)&muf[16+kofA+4];
      part = fmaf(blof(a_h0.u.x,a_l0.u.x), m0.x, part);
      part = fmaf(bhif(a_h0.u.x,a_l0.u.x), m0.y, part);
      part = fmaf(blof(a_h0.u.y,a_l0.u.y), m0.z, part);
      part = fmaf(bhif(a_h0.u.y,a_l0.u.y), m0.w, part);
      part = fmaf(blof(a_h0.u.z,a_l0.u.z), m1.x, part);
      part = fmaf(bhif(a_h0.u.z,a_l0.u.z), m1.y, part);
      part = fmaf(blof(a_h0.u.w,a_l0.u.w), m1.z, part);
      part = fmaf(bhif(a_h0.u.w,a_l0.u.w), m1.w, part);
      part = fmaf(blof(a_h1.u.x,a_l1.u.x), m2.x, part);
      part = fmaf(bhif(a_h1.u.x,a_l1.u.x), m2.y, part);
      part = fmaf(blof(a_h1.u.y,a_l1.u.y), m2.z, part);
      part = fmaf(bhif(a_h1.u.y,a_l1.u.y), m2.w, part);
      part = fmaf(blof(a_h1.u.z,a_l1.u.z), m3.x, part);
      part = fmaf(bhif(a_h1.u.z,a_l1.u.z), m3.y, part);
      part = fmaf(blof(a_h1.u.w,a_l1.u.w), m3.z, part);
      part = fmaf(bhif(a_h1.u.w,a_l1.u.w), m3.w, part);
    }
    part += __shfl_xor(part, 32);
    {
      float4 b0 = *(const float4*)&Bm[c32][0];
      float4 b1 = *(const float4*)&Bm[c32][4];
      float4 u0 = *(const float4*)&uvf[0];
      float4 u1 = *(const float4*)&uvf[4];
      part = fmaf(b0.x,u0.x, fmaf(b0.y,u0.y, fmaf(b0.z,u0.z, fmaf(b0.w,u0.w, part))));
      part = fmaf(b1.x,u1.x, fmaf(b1.y,u1.y, fmaf(b1.z,u1.z, fmaf(b1.w,u1.w, part))));
    }
    if (l < 32){ mupf[c32] = part; wsMu[bt*32 + c32] = part; }

    // ---- P2': Sigma_p = A * U + Q  (B-frags of U built in-register) ----
    U8 b_h0, b_h1, b_l0, b_l1;
    DLAYOUT_TO_BFRAG(uu, h, b_h0, b_l0, b_h1, b_l1);
    f32x16 spa, spb;
    #pragma unroll
    for (int r=0;r<16;++r){ spa[r] = 0.f; spb[r] = 0.f; }
    spa = mfma32(a_h0.b, b_h0.b, spa);
    spa = mfma32(a_h0.b, b_l0.b, spa);
    spa = mfma32(a_l0.b, b_h0.b, spa);
    spb = mfma32(a_h1.b, b_h1.b, spb);
    spb = mfma32(a_h1.b, b_l1.b, spb);
    spb = mfma32(a_l1.b, b_h1.b, spb);
    f32x16 sp;
    #pragma unroll
    for (int r=0;r<16;++r){
      int rr = (r&3) + 8*(r>>2) + 4*h;
      sp[r] = spa[r] + spb[r] + ((rr == c32) ? 0.01f : 0.f);
    }
    {
      float* wp = wsSig + (bt*32 + c32)*32;
      *(float4*)(wp + 0  + 4*h) = make_float4(sp[0], sp[1], sp[2], sp[3]);
      *(float4*)(wp + 8  + 4*h) = make_float4(sp[4], sp[5], sp[6], sp[7]);
      *(float4*)(wp + 16 + 4*h) = make_float4(sp[8], sp[9], sp[10],sp[11]);
      *(float4*)(wp + 24 + 4*h) = make_float4(sp[12],sp[13],sp[14],sp[15]);
      #pragma unroll
      for (int gq=0; gq<4; ++gq){
        uint2v hw, lw;
        hw.x = hipack(sp[4*gq+0], sp[4*gq+1]); hw.y = hipack(sp[4*gq+2], sp[4*gq+3]);
        lw.x = lopack(sp[4*gq+0], sp[4*gq+1]); lw.y = lopack(sp[4*gq+2], sp[4*gq+3]);
        *(uint2v*)&Phi[c32][8*gq + 4*h] = hw;
        *(uint2v*)&Plo[c32][8*gq + 4*h] = lw;
      }
    }

    // ---- P3: CS = C * Sigma_p ----
    U8 c_h, c_l, p_h0, p_l0, p_h1, p_l1;
    c_h.u  = *(const uint4v*)&Chi[c16][kofC];
    c_l.u  = *(const uint4v*)&Clo[c16][kofC];
    p_h0.u = *(const uint4v*)&Phi[c16][kofC];
    p_l0.u = *(const uint4v*)&Plo[c16][kofC];
    p_h1.u = *(const uint4v*)&Phi[16+c16][kofC];
    p_l1.u = *(const uint4v*)&Plo[16+c16][kofC];
    f32x4 cs0, cs1;
    #pragma unroll
    for (int r=0;r<4;++r){ cs0[r]=0.f; cs1[r]=0.f; }
    cs0 = mfma16(c_h.b, p_h0.b, cs0);
    cs0 = mfma16(c_h.b, p_l0.b, cs0);
    cs0 = mfma16(c_l.b, p_h0.b, cs0);
    cs1 = mfma16(c_h.b, p_h1.b, cs1);
    cs1 = mfma16(c_h.b, p_l1.b, cs1);
    cs1 = mfma16(c_l.b, p_h1.b, cs1);
    #pragma unroll
    for (int r=0;r<4;++r){
      int rr = q4*4 + r;
      ZP[rr][c16]     = packhl(cs0[r]);
      ZP[rr][16+c16]  = packhl(cs1[r]);
      CSf[rr][c16]    = cs0[r];
      CSf[rr][16+c16] = cs1[r];
    }
    {
      uint2v hw0, lw0, hw1, lw1;
      hw0.x = hipack(cs0[0],cs0[1]); hw0.y = hipack(cs0[2],cs0[3]);
      lw0.x = lopack(cs0[0],cs0[1]); lw0.y = lopack(cs0[2],cs0[3]);
      hw1.x = hipack(cs1[0],cs1[1]); hw1.y = hipack(cs1[2],cs1[3]);
      lw1.x = lopack(cs1[0],cs1[1]); lw1.y = lopack(cs1[2],cs1[3]);
      *(uint2v*)&Yhi[c16][q4*4]    = hw0; *(uint2v*)&Ylo[c16][q4*4]    = lw0;
      *(uint2v*)&Yhi[16+c16][q4*4] = hw1; *(uint2v*)&Ylo[16+c16][q4*4] = lw1;
    }
    // r = y - C*mu_p
    {
      float prr = 0.f;
      float4 m0 = *(const float4*)&mupf[kofC];
      float4 m1 = *(const float4*)&mupf[kofC+4];
      prr = fmaf(blof(c_h.u.x,c_l.u.x), m0.x, prr);
      prr = fmaf(bhif(c_h.u.x,c_l.u.x), m0.y, prr);
      prr = fmaf(blof(c_h.u.y,c_l.u.y), m0.z, prr);
      prr = fmaf(bhif(c_h.u.y,c_l.u.y), m0.w, prr);
      prr = fmaf(blof(c_h.u.z,c_l.u.z), m1.x, prr);
      prr = fmaf(bhif(c_h.u.z,c_l.u.z), m1.y, prr);
      prr = fmaf(blof(c_h.u.w,c_l.u.w), m1.z, prr);
      prr = fmaf(bhif(c_h.u.w,c_l.u.w), m1.w, prr);
      prr += __shfl_xor(prr, 16);
      prr += __shfl_xor(prr, 32);
      if (l < 16) rvf[l] = yvf[l] - prr;
    }

    // ---- P4: S = CS * C^T + R ----
    {
      U8 z_h, z_l;
      uint4v pz0 = *(const uint4v*)&ZP[c16][kofC];
      uint4v pz1 = *(const uint4v*)&ZP[c16][kofC+4];
      z_h.u = frag_hi(pz0, pz1); z_l.u = frag_lo(pz0, pz1);
      f32x4 ss;
      #pragma unroll
      for (int r=0;r<4;++r) ss[r] = 0.f;
      ss = mfma16(z_h.b, c_h.b, ss);
      ss = mfma16(z_h.b, c_l.b, ss);
      ss = mfma16(z_l.b, c_h.b, ss);
      #pragma unroll
      for (int r=0;r<4;++r){
        int rr = q4*4 + r;
        SLf[rr][c16] = ss[r] + ((rr == c16) ? 0.01f : 0.f);
      }
    }

    // ---- prefetch next-step inputs ----
    float4 pa0, pa1, pa2, pa3, pc0, pc1, pbv;
    float py = 0.f, pu = 0.f;
    pa0=pa1=pa2=pa3=make_float4(0.f,0.f,0.f,0.f);
    pc0=pc1=pbv=make_float4(0.f,0.f,0.f,0.f);
    if (t + 1 < TT){
      const float* ap = Ag + (bt+1)*1024 + rA*32 + cA;
      pa0 = *(const float4*)(ap+0);  pa1 = *(const float4*)(ap+4);
      pa2 = *(const float4*)(ap+8);  pa3 = *(const float4*)(ap+12);
      const float* cp = Cg + (bt+1)*512 + rC*32 + cC;
      pc0 = *(const float4*)(cp+0);  pc1 = *(const float4*)(cp+4);
      pbv = *(const float4*)(Bg + (bt+1)*256 + (l>>1)*8 + (l&1)*4);
      if (l < 16) py = Yg[(bt+1)*16 + l];
      if (l < 8)  pu = Ug[(bt+1)*8 + l];
    }

    // ---- P5: column-layout Gauss-Jordan via readlane (no shuffles) ----
    {
      float aug[16];
      if (l < 16){
        #pragma unroll
        for (int i=0;i<16;++i) aug[i] = 0.5f*(SLf[i][l] + SLf[l][i]);
      } else if (l < 48){
        #pragma unroll
        for (int i=0;i<16;++i) aug[i] = CSf[i][l-16];
      } else {
        #pragma unroll
        for (int i=0;i<16;++i) aug[i] = 0.f;
      }
      #pragma unroll
      for (int k=0;k<16;++k){
        float piv = rdl(aug[k], k);
        float q = -aug[k] * frcp(piv);
        #pragma unroll
        for (int i=0;i<16;++i){
          if (i == k) continue;
          float s = rdl(aug[i], k);
          aug[i] = fmaf(q, s, aug[i]);
        }
      }
      if (l >= 16 && l < 48){
        #pragma unroll
        for (int i=0;i<16;++i){
          float d = rdl(aug[i], i);
          KtTP[l-16][i] = packhl(-aug[i] * frcp(d));
        }
      }
    }

    // ---- P6: Sigma_f = Sigma_p - CS^T * Kt ----
    f32x16 sf = sp;
    {
      U8 y_h, y_l, kt_h, kt_l;
      y_h.u = *(const uint4v*)&Yhi[c32][8*h];
      y_l.u = *(const uint4v*)&Ylo[c32][8*h];
      uint4v k0, k1;
      { uint2v a0 = *(const uint2v*)&KtTP[c32][8*h];
        uint2v a1 = *(const uint2v*)&KtTP[c32][8*h+2];
        uint2v a2 = *(const uint2v*)&KtTP[c32][8*h+4];
        uint2v a3 = *(const uint2v*)&KtTP[c32][8*h+6];
        k0.x=a0.x; k0.y=a0.y; k0.z=a1.x; k0.w=a1.y;
        k1.x=a2.x; k1.y=a2.y; k1.z=a3.x; k1.w=a3.y; }
      kt_h.u = frag_hi(k0, k1); kt_l.u = frag_lo(k0, k1);
      sf = mfma32(y_h.b, kt_h.b, sf);
      sf = mfma32(y_h.b, kt_l.b, sf);
      sf = mfma32(y_l.b, kt_h.b, sf);
    }
    #pragma unroll
    for (int gq=0; gq<4; ++gq){
      uint2v hw, lw;
      hw.x = hipack(sf[4*gq+0], sf[4*gq+1]); hw.y = hipack(sf[4*gq+2], sf[4*gq+3]);
      lw.x = lopack(sf[4*gq+0], sf[4*gq+1]); lw.y = lopack(sf[4*gq+2], sf[4*gq+3]);
      *(uint2v*)&Ghi[c32][8*gq + 4*h] = hw;
      *(uint2v*)&Glo[c32][8*gq + 4*h] = lw;
    }
    {
      float* ob = outg + (bt*32)*33;
      #pragma unroll
      for (int r=0;r<16;++r){
        int rr = (r&3) + 8*(r>>2) + 4*h;
        ob[rr*33 + 1 + c32] = sf[r];
      }
      float mf = mupf[c32];
      #pragma unroll
      for (int p=0;p<16;++p){
        unsigned int w = KtTP[c32][p];
        mf = fmaf(-unpk(w), rvf[p], mf);
      }
      if (l < 32){ muf[c32] = mf; ob[c32*33] = mf; }
    }

    // ---- P7: stage next-step inputs ----
    if (t + 1 < TT){
      split16(pa0, pa1, pa2, pa3, &Ahi[rA][cA], &Alo[rA][cA]);
      split8(pc0, pc1, &Chi[rC][cC], &Clo[rC][cC]);
      *(float4*)&Bm[l>>1][(l&1)*4] = pbv;
      if (l < 16) yvf[l] = py;
      if (l < 8)  uvf[l] = pu;
    }
  }
}

// ===== Smoother precompute: 1 WAVE per (b,t), readlane-GJ inversion, MFMA (unchanged R8) =====
__global__ __launch_bounds__(64) void kf_precomp(
    const float* __restrict__ Ag, float* __restrict__ outg,
    float* __restrict__ wsSig, const float* __restrict__ wsMu)
{
  const int t = blockIdx.x;        // 0..126
  const int b = blockIdx.y;
  const int l = threadIdx.x;
  const int c32 = l & 31;
  const int h = l >> 5;
  const int kofA = h * 8;

  __shared__ __align__(16) float        Sffr[1060];
  __shared__ __align__(16) unsigned int MmP[32][34];
  __shared__ __align__(16) unsigned int VPT[32][34];
  __shared__ __align__(16) unsigned int JP [32][34];
  __shared__ float mp1f[32];

  const size_t bt = (size_t)b*TT + t;
  float* osl = outg + bt*1056;

  {
    const float4* src = (const float4*)osl;
    #pragma unroll
    for (int q=0;q<4;++q) *(float4*)&Sffr[(l + 64*q)*4] = src[l + 64*q];
    if (l < 8) *(float4*)&Sffr[(l + 256)*4] = src[l + 256];
    if (l < 32) mp1f[l] = wsMu[(bt+1)*32 + l];
  }

  float aug[32];
  if (l < 32){
    const float* pp = wsSig + (bt+1)*1024 + (size_t)l*32;
    #pragma unroll
    for (int q=0;q<8;++q){
      float4 v = *(const float4*)(pp + 4*q);
      aug[4*q]=v.x; aug[4*q+1]=v.y; aug[4*q+2]=v.z; aug[4*q+3]=v.w;
    }
  } else {
    #pragma unroll
    for (int i=0;i<32;++i) aug[i] = (i == l-32) ? 1.f : 0.f;
  }

  U8 a_h0, a_l0, a_h1, a_l1;
  {
    const float* ap = Ag + bt*1024 + c32*32;
    float4 v0 = *(const float4*)(ap + kofA);
    float4 v1 = *(const float4*)(ap + kofA + 4);
    float4 v2 = *(const float4*)(ap + 16 + kofA);
    float4 v3 = *(const float4*)(ap + 16 + kofA + 4);
    MK8(v0, v1, a_h0, a_l0);
    MK8(v2, v3, a_h1, a_l1);
  }
  U8 s_h0, s_l0, s_h1, s_l1;
  {
    const float* rp = &Sffr[c32*33 + 1];
    float4 v0, v1, v2, v3;
    v0.x=rp[kofA+0]; v0.y=rp[kofA+1]; v0.z=rp[kofA+2]; v0.w=rp[kofA+3];
    v1.x=rp[kofA+4]; v1.y=rp[kofA+5]; v1.z=rp[kofA+6]; v1.w=rp[kofA+7];
    v2.x=rp[16+kofA+0]; v2.y=rp[16+kofA+1]; v2.z=rp[16+kofA+2]; v2.w=rp[16+kofA+3];
    v3.x=rp[16+kofA+4]; v3.y=rp[16+kofA+5]; v3.z=rp[16+kofA+6]; v3.w=rp[16+kofA+7];
    MK8(v0, v1, s_h0, s_l0);
    MK8(v2, v3, s_h1, s_l1);
  }

  f32x16 ma, mb;
  #pragma unroll
  for (int r=0;r<16;++r){ ma[r]=0.f; mb[r]=0.f; }
  ma = mfma32(s_h0.b, a_h0.b, ma);
  ma = mfma32(s_h0.b, a_l0.b, ma);
  ma = mfma32(s_l0.b, a_h0.b, ma);
  mb = mfma32(s_h1.b, a_h1.b, mb);
  mb = mfma32(s_h1.b, a_l1.b, mb);
  mb = mfma32(s_l1.b, a_h1.b, mb);
  #pragma unroll
  for (int r=0;r<16;++r){
    int rr = (r&3) + 8*(r>>2) + 4*h;
    MmP[rr][c32] = packhl(ma[r] + mb[r]);
  }

  #pragma unroll
  for (int k=0;k<32;++k){
    float piv = rdl(aug[k], k);
    float q = -aug[k] * frcp(piv);
    #pragma unroll
    for (int i=0;i<32;++i){
      if (i == k) continue;
      float s = rdl(aug[i], k);
      aug[i] = fmaf(q, s, aug[i]);
    }
  }
  if (l >= 32){
    #pragma unroll
    for (int i=0;i<32;++i){
      float d = rdl(aug[i], i);
      VPT[l-32][i] = packhl(aug[i] * frcp(d));
    }
  }

  U8 m_h0, m_l0, m_h1, m_l1;
  {
    uint4v ua, ub, uc, ud;
    ua.x=MmP[c32][kofA+0]; ua.y=MmP[c32][kofA+1]; ua.z=MmP[c32][kofA+2]; ua.w=MmP[c32][kofA+3];
    ub.x=MmP[c32][kofA+4]; ub.y=MmP[c32][kofA+5]; ub.z=MmP[c32][kofA+6]; ub.w=MmP[c32][kofA+7];
    uc.x=MmP[c32][16+kofA+0]; uc.y=MmP[c32][16+kofA+1]; uc.z=MmP[c32][16+kofA+2]; uc.w=MmP[c32][16+kofA+3];
    ud.x=MmP[c32][16+kofA+4]; ud.y=MmP[c32][16+kofA+5]; ud.z=MmP[c32][16+kofA+6]; ud.w=MmP[c32][16+kofA+7];
    m_h0.u = frag_hi(ua, ub); m_l0.u = frag_lo(ua, ub);
    m_h1.u = frag_hi(uc, ud); m_l1.u = frag_lo(uc, ud);
  }
  U8 v_h0, v_l0, v_h1, v_l1;
  {
    uint4v ua, ub, uc, ud;
    ua.x=VPT[c32][kofA+0]; ua.y=VPT[c32][kofA+1]; ua.z=VPT[c32][kofA+2]; ua.w=VPT[c32][kofA+3];
    ub.x=VPT[c32][kofA+4]; ub.y=VPT[c32][kofA+5]; ub.z=VPT[c32][kofA+6]; ub.w=VPT[c32][kofA+7];
    uc.x=VPT[c32][16+kofA+0]; uc.y=VPT[c32][16+kofA+1]; uc.z=VPT[c32][16+kofA+2]; uc.w=VPT[c32][16+kofA+3];
    ud.x=VPT[c32][16+kofA+4]; ud.y=VPT[c32][16+kofA+5]; ud.z=VPT[c32][16+kofA+6]; ud.w=VPT[c32][16+kofA+7];
    v_h0.u = frag_hi(ua, ub); v_l0.u = frag_lo(ua, ub);
    v_h1.u = frag_hi(uc, ud); v_l1.u = frag_lo(uc, ud);
  }
  f32x16 ja, jb;
  #pragma unroll
  for (int r=0;r<16;++r){ ja[r]=0.f; jb[r]=0.f; }
  ja = mfma32(m_h0.b, v_h0.b, ja);
  ja = mfma32(m_h0.b, v_l0.b, ja);
  ja = mfma32(m_l0.b, v_h0.b, ja);
  jb = mfma32(m_h1.b, v_h1.b, jb);
  jb = mfma32(m_h1.b, v_l1.b, jb);
  jb = mfma32(m_l1.b, v_h1.b, jb);
  {
    float* jws = wsSig + (bt+1)*1024;
    #pragma unroll
    for (int r=0;r<16;++r){
      int rr = (r&3) + 8*(r>>2) + 4*h;
      float jv = ja[r] + jb[r];
      jws[rr*32 + c32] = jv;
      JP[rr][c32] = packhl(-jv);
    }
  }

  U8 nj_h0, nj_l0, nj_h1, nj_l1;
  {
    uint4v ua, ub, uc, ud;
    ua.x=JP[c32][kofA+0]; ua.y=JP[c32][kofA+1]; ua.z=JP[c32][kofA+2]; ua.w=JP[c32][kofA+3];
    ub.x=JP[c32][kofA+4]; ub.y=JP[c32][kofA+5]; ub.z=JP[c32][kofA+6]; ub.w=JP[c32][kofA+7];
    uc.x=JP[c32][16+kofA+0]; uc.y=JP[c32][16+kofA+1]; uc.z=JP[c32][16+kofA+2]; uc.w=JP[c32][16+kofA+3];
    ud.x=JP[c32][16+kofA+4]; ud.y=JP[c32][16+kofA+5]; ud.z=JP[c32][16+kofA+6]; ud.w=JP[c32][16+kofA+7];
    nj_h0.u = frag_hi(ua, ub); nj_l0.u = frag_lo(ua, ub);
    nj_h1.u = frag_hi(uc, ud); nj_l1.u = frag_lo(uc, ud);
  }
  f32x16 ea, eb;
  #pragma unroll
  for (int r=0;r<16;++r){
    int rr = (r&3) + 8*(r>>2) + 4*h;
    ea[r] = Sffr[rr*33 + 1 + c32];
    eb[r] = 0.f;
  }
  ea = mfma32(m_h0.b, nj_h0.b, ea);
  ea = mfma32(m_h0.b, nj_l0.b, ea);
  ea = mfma32(m_l0.b, nj_h0.b, ea);
  eb = mfma32(m_h1.b, nj_h1.b, eb);
  eb = mfma32(m_h1.b, nj_l1.b, eb);
  eb = mfma32(m_l1.b, nj_h1.b, eb);
  #pragma unroll
  for (int r=0;r<16;++r){
    int rr = (r&3) + 8*(r>>2) + 4*h;
    osl[rr*33 + 1 + c32] = ea[r] + eb[r];
  }

  {
    float e2 = Sffr[c32*33];
    #pragma unroll
    for (int k=0;k<32;++k)
      e2 = fmaf(unpk(JP[c32][k]), mp1f[k], e2);
    if (l < 32) osl[c32*33] = e2;
  }
}

// ===== Backward smoother: 1 wave = TWO batches (ILP), J direct-from-global =====
__global__ __launch_bounds__(64) void kf_backward(
    float* __restrict__ outg, const float* __restrict__ wsSig)
{
  const int l   = threadIdx.x;
  const int c32 = l & 31;
  const int h   = l >> 5;
  const int kofA = h * 8;
  const int rA = l >> 1, cA = (l & 1) << 4;

  __shared__ __align__(16) unsigned int SP[2][32][36];
  __shared__ float muv[2][32];

  size_t base[2];
  base[0] = (size_t)(blockIdx.x*2 + 0) * TT;
  base[1] = (size_t)(blockIdx.x*2 + 1) * TT;

  float er[2][16]; float ev[2];
  float4 pj[2][4];

  #pragma unroll
  for (int bb=0;bb<2;++bb){
    const float* os = outg + (base[bb] + TT - 1)*1056;
    const float* rp = os + rA*33 + 1 + cA;
    float4 v0 = *(const float4*)(rp+0), v1 = *(const float4*)(rp+4),
           v2 = *(const float4*)(rp+8), v3 = *(const float4*)(rp+12);
    uint4v u0, u1;
    u0.x = packhl(v0.x); u0.y = packhl(v0.y); u0.z = packhl(v0.z); u0.w = packhl(v0.w);
    u1.x = packhl(v1.x); u1.y = packhl(v1.y); u1.z = packhl(v1.z); u1.w = packhl(v1.w);
    *(uint4v*)&SP[bb][rA][cA+0] = u0; *(uint4v*)&SP[bb][rA][cA+4] = u1;
    u0.x = packhl(v2.x); u0.y = packhl(v2.y); u0.z = packhl(v2.z); u0.w = packhl(v2.w);
    u1.x = packhl(v3.x); u1.y = packhl(v3.y); u1.z = packhl(v3.z); u1.w = packhl(v3.w);
    *(uint4v*)&SP[bb][rA][cA+8] = u0; *(uint4v*)&SP[bb][rA][cA+12] = u1;
    if (l < 32) muv[bb][l] = os[l*33];
    // J_{T-2} rows direct from global (slot base+T-1), lane-row layout
    const float* jp = wsSig + (base[bb] + TT - 1)*1024 + c32*32;
    pj[bb][0] = *(const float4*)(jp + kofA);
    pj[bb][1] = *(const float4*)(jp + kofA + 4);
    pj[bb][2] = *(const float4*)(jp + 16 + kofA);
    pj[bb][3] = *(const float4*)(jp + 16 + kofA + 4);
    const float* oe = outg + (base[bb] + TT - 2)*1056;
    #pragma unroll
    for (int r=0;r<16;++r){
      int rr = (r&3) + 8*(r>>2) + 4*h;
      er[bb][r] = oe[rr*33 + 1 + c32];
    }
    ev[bb] = (l < 32) ? oe[l*33] : 0.f;
  }

  for (int t = TT - 2; t >= 0; --t) {
    // ---- prefetch next iteration for both batches ----
    float4 nj[2][4]; float ner[2][16]; float nev[2];
    if (t > 0) {
      #pragma unroll
      for (int bb=0;bb<2;++bb){
        const float* jp = wsSig + (base[bb] + t)*1024 + c32*32;
        nj[bb][0] = *(const float4*)(jp + kofA);
        nj[bb][1] = *(const float4*)(jp + kofA + 4);
        nj[bb][2] = *(const float4*)(jp + 16 + kofA);
        nj[bb][3] = *(const float4*)(jp + 16 + kofA + 4);
        const float* oe = outg + (base[bb] + t - 1)*1056;
        #pragma unroll
        for (int r=0;r<16;++r){
          int rr = (r&3) + 8*(r>>2) + 4*h;
          ner[bb][r] = oe[rr*33 + 1 + c32];
        }
        nev[bb] = (l < 32) ? oe[l*33] : 0.f;
      }
    } else {
      #pragma unroll
      for (int bb=0;bb<2;++bb){
        nj[bb][0]=nj[bb][1]=nj[bb][2]=nj[bb][3]=make_float4(0.f,0.f,0.f,0.f);
        #pragma unroll
        for (int r=0;r<16;++r) ner[bb][r] = 0.f;
        nev[bb] = 0.f;
      }
    }

    // ---- J fragments for both batches (in-register, no LDS) ----
    U8 aH0[2], aL0[2], aH1[2], aL1[2];
    #pragma unroll
    for (int bb=0;bb<2;++bb){
      MK8(pj[bb][0], pj[bb][1], aH0[bb], aL0[bb]);
      MK8(pj[bb][2], pj[bb][3], aH1[bb], aL1[bb]);
    }

    // ---- W' = Sigma_s * J^T for both batches ----
    float ww[2][16];
    #pragma unroll
    for (int bb=0;bb<2;++bb){
      U8 s_h0, s_l0, s_h1, s_l1;
      uint4v ua = *(const uint4v*)&SP[bb][c32][0  + kofA];
      uint4v ub = *(const uint4v*)&SP[bb][c32][4  + kofA];
      uint4v uc = *(const uint4v*)&SP[bb][c32][16 + kofA];
      uint4v ud = *(const uint4v*)&SP[bb][c32][20 + kofA];
      s_h0.u = frag_hi(ua, ub); s_l0.u = frag_lo(ua, ub);
      s_h1.u = frag_hi(uc, ud); s_l1.u = frag_lo(uc, ud);
      f32x16 wa, wb;
      #pragma unroll
      for (int r=0;r<16;++r){ wa[r]=0.f; wb[r]=0.f; }
      wa = mfma32(s_h0.b, aH0[bb].b, wa);
      wa = mfma32(s_h0.b, aL0[bb].b, wa);
      wa = mfma32(s_l0.b, aH0[bb].b, wa);
      wb = mfma32(s_h1.b, aH1[bb].b, wb);
      wb = mfma32(s_h1.b, aL1[bb].b, wb);
      wb = mfma32(s_l1.b, aH1[bb].b, wb);
      #pragma unroll
      for (int r=0;r<16;++r) ww[bb][r] = wa[r] + wb[r];
    }

    // ---- G = E + J * W' ; mu ; stores ; state update for both batches ----
    #pragma unroll
    for (int bb=0;bb<2;++bb){
      U8 bw_h0, bw_l0, bw_h1, bw_l1;
      DLAYOUT_TO_BFRAG(ww[bb], h, bw_h0, bw_l0, bw_h1, bw_l1);
      f32x16 ga, gb;
      #pragma unroll
      for (int r=0;r<16;++r){ ga[r] = er[bb][r]; gb[r] = 0.f; }
      ga = mfma32(aH0[bb].b, bw_h0.b, ga);
      ga = mfma32(aH0[bb].b, bw_l0.b, ga);
      ga = mfma32(aL0[bb].b, bw_h0.b, ga);
      gb = mfma32(aH1[bb].b, bw_h1.b, gb);
      gb = mfma32(aH1[bb].b, bw_l1.b, gb);
      gb = mfma32(aL1[bb].b, bw_h1.b, gb);

      // mu_s = e + J * mu_s
      float part = 0.f;
      {
        float4 m0 = *(const float4*)&muv[bb][kofA];
        float4 m1 = *(const float4*)&muv[bb][kofA+4];
        float4 m2 = *(const float4*)&muv[bb][16+kofA];
        float4 m3 = *(const float4*)&muv[bb][16+kofA+4];
        part = fmaf(blof(aH0[bb].u.x,aL0[bb].u.x), m0.x, part);
        part = fmaf(bhif(aH0[bb].u.x,aL0[bb].u.x), m0.y, part);
        part = fmaf(blof(aH0[bb].u.y,aL0[bb].u.y), m0.z, part);
        part = fmaf(bhif(aH0[bb].u.y,aL0[bb].u.y), m0.w, part);
        part = fmaf(blof(aH0[bb].u.z,aL0[bb].u.z), m1.x, part);
        part = fmaf(bhif(aH0[bb].u.z,aL0[bb].u.z), m1.y, part);
        part = fmaf(blof(aH0[bb].u.w,aL0[bb].u.w), m1.z, part);
        part = fmaf(bhif(aH0[bb].u.w,aL0[bb].u.w), m1.w, part);
        part = fmaf(blof(aH1[bb].u.x,aL1[bb].u.x), m2.x, part);
        part = fmaf(bhif(aH1[bb].u.x,aL1[bb].u.x), m2.y, part);
        part = fmaf(blof(aH1[bb].u.y,aL1[bb].u.y), m2.z, part);
        part = fmaf(bhif(aH1[bb].u.y,aL1[bb].u.y), m2.w, part);
        part = fmaf(blof(aH1[bb].u.z,aL1[bb].u.z), m3.x, part);
        part = fmaf(bhif(aH1[bb].u.z,aL1[bb].u.z), m3.y, part);
        part = fmaf(blof(aH1[bb].u.w,aL1[bb].u.w), m3.z, part);
        part = fmaf(bhif(aH1[bb].u.w,aL1[bb].u.w), m3.w, part);
      }
      part += __shfl_xor(part, 32);
      float mn = ev[bb] + part;

      {
        float* ob = outg + (base[bb] + t)*1056;
        #pragma unroll
        for (int r=0;r<16;++r){
          int rr = (r&3) + 8*(r>>2) + 4*h;
          ob[rr*33 + 1 + c32] = ga[r] + gb[r];
        }
        #pragma unroll
        for (int gq=0; gq<4; ++gq){
          uint4v uw;
          uw.x = packhl(ga[4*gq+0]+gb[4*gq+0]); uw.y = packhl(ga[4*gq+1]+gb[4*gq+1]);
          uw.z = packhl(ga[4*gq+2]+gb[4*gq+2]); uw.w = packhl(ga[4*gq+3]+gb[4*gq+3]);
          *(uint4v*)&SP[bb][c32][8*gq + 4*h] = uw;
        }
        if (l < 32){ muv[bb][l] = mn; ob[l*33] = mn; }
      }

      if (t > 0){
        #pragma unroll
        for (int q=0;q<4;++q) pj[bb][q] = nj[bb][q];
        #pragma unroll
        for (int r=0;r<16;++r) er[bb][r] = ner[bb][r];
        ev[bb] = nev[bb];
      }
    }
  }
}

extern "C" void kernel_launch(void* const* d_in, const int* in_sizes, int n_in,
                              void* d_out, int out_size, void* d_ws, size_t ws_size,
                              hipStream_t stream) {
  (void)in_sizes; (void)n_in; (void)out_size; (void)ws_size;
  const float* Yg   = (const float*)d_in[0];
  const float* Ug   = (const float*)d_in[1];
  const float* Ag   = (const float*)d_in[2];
  const float* Bg   = (const float*)d_in[3];
  const float* Cg   = (const float*)d_in[4];
  const float* mu0g = (const float*)d_in[5];
  const float* S0g  = (const float*)d_in[6];
  float* outg = (float*)d_out;
  float* wsSig = (float*)d_ws;
  float* wsMu  = wsSig + (size_t)NB*TT*NSZ*NSZ;

  hipLaunchKernelGGL(kf_forward, dim3(NB), dim3(64), 0, stream,
                     Yg, Ug, Ag, Bg, Cg, mu0g, S0g, outg, wsSig, wsMu);
  hipLaunchKernelGGL(kf_precomp, dim3(TT-1, NB), dim3(64), 0, stream,
                     Ag, outg, wsSig, wsMu);
  hipLaunchKernelGGL(kf_backward, dim3(NB/2), dim3(64), 0, stream,
                     outg, wsSig);
}

// Round 10
// 691.589 us; speedup vs baseline: 1.2174x; 1.2174x over previous
//
#include <hip/hip_runtime.h>

#define TT 128
#define NB 64
#define NSZ 32
#define MSZ 8
#define PSZ 16

typedef __attribute__((ext_vector_type(8)))  short bf16x8;
typedef __attribute__((ext_vector_type(16))) float f32x16;
typedef __attribute__((ext_vector_type(4)))  float f32x4;
typedef __attribute__((ext_vector_type(4)))  unsigned int uint4v;
typedef __attribute__((ext_vector_type(2)))  unsigned int uint2v;

union U8 { uint4v u; bf16x8 b; };

__device__ __forceinline__ float frcp(float x){ return __builtin_amdgcn_rcpf(x); }
__device__ __forceinline__ float rdl(float x, int lane){
  return __int_as_float(__builtin_amdgcn_readlane(__float_as_int(x), lane));
}

// bf16 split helpers: hi = truncated top-16 of f32; lo = bf16(x - f32(hi)).
__device__ __forceinline__ unsigned int hipack(float x0, float x1){
  return __builtin_amdgcn_perm(__float_as_uint(x1), __float_as_uint(x0), 0x07060302u);
}
__device__ __forceinline__ unsigned int lopack(float x0, float x1){
  float l0 = x0 - __uint_as_float(__float_as_uint(x0) & 0xFFFF0000u);
  float l1 = x1 - __uint_as_float(__float_as_uint(x1) & 0xFFFF0000u);
  return __builtin_amdgcn_perm(__float_as_uint(l1), __float_as_uint(l0), 0x07060302u);
}
__device__ __forceinline__ unsigned int packhl(float x){
  unsigned int u = __float_as_uint(x);
  unsigned int h = u & 0xFFFF0000u;
  float xl = x - __uint_as_float(h);
  return h | (__float_as_uint(xl) >> 16);
}
__device__ __forceinline__ float unpk(unsigned int u){
  return __uint_as_float(u & 0xFFFF0000u) + __uint_as_float(u << 16);
}
__device__ __forceinline__ uint4v frag_hi(uint4v a, uint4v b){
  uint4v r;
  r.x = __builtin_amdgcn_perm(a.y, a.x, 0x07060302u);
  r.y = __builtin_amdgcn_perm(a.w, a.z, 0x07060302u);
  r.z = __builtin_amdgcn_perm(b.y, b.x, 0x07060302u);
  r.w = __builtin_amdgcn_perm(b.w, b.z, 0x07060302u);
  return r;
}
__device__ __forceinline__ uint4v frag_lo(uint4v a, uint4v b){
  uint4v r;
  r.x = __builtin_amdgcn_perm(a.y, a.x, 0x05040100u);
  r.y = __builtin_amdgcn_perm(a.w, a.z, 0x05040100u);
  r.z = __builtin_amdgcn_perm(b.y, b.x, 0x05040100u);
  r.w = __builtin_amdgcn_perm(b.w, b.z, 0x05040100u);
  return r;
}
__device__ __forceinline__ float blof(unsigned int h, unsigned int l){
  return __uint_as_float(h << 16) + __uint_as_float(l << 16);
}
__device__ __forceinline__ float bhif(unsigned int h, unsigned int l){
  return __uint_as_float(h & 0xFFFF0000u) + __uint_as_float(l & 0xFFFF0000u);
}
__device__ __forceinline__ f32x16 mfma32(bf16x8 a, bf16x8 b, f32x16 c){
  return __builtin_amdgcn_mfma_f32_32x32x16_bf16(a, b, c, 0, 0, 0);
}
__device__ __forceinline__ f32x4 mfma16(bf16x8 a, bf16x8 b, f32x4 c){
  return __builtin_amdgcn_mfma_f32_16x16x32_bf16(a, b, c, 0, 0, 0);
}
__device__ __forceinline__ void split16(float4 v0, float4 v1, float4 v2, float4 v3,
                                        unsigned short* hi, unsigned short* lo){
  uint4v hw0, hw1, lw0, lw1;
  hw0.x=hipack(v0.x,v0.y); hw0.y=hipack(v0.z,v0.w); hw0.z=hipack(v1.x,v1.y); hw0.w=hipack(v1.z,v1.w);
  hw1.x=hipack(v2.x,v2.y); hw1.y=hipack(v2.z,v2.w); hw1.z=hipack(v3.x,v3.y); hw1.w=hipack(v3.z,v3.w);
  lw0.x=lopack(v0.x,v0.y); lw0.y=lopack(v0.z,v0.w); lw0.z=lopack(v1.x,v1.y); lw0.w=lopack(v1.z,v1.w);
  lw1.x=lopack(v2.x,v2.y); lw1.y=lopack(v2.z,v2.w); lw1.z=lopack(v3.x,v3.y); lw1.w=lopack(v3.z,v3.w);
  *(uint4v*)hi = hw0; *(uint4v*)(hi+8) = hw1;
  *(uint4v*)lo = lw0; *(uint4v*)(lo+8) = lw1;
}
__device__ __forceinline__ void split8(float4 v0, float4 v1,
                                       unsigned short* hi, unsigned short* lo){
  uint4v hw, lw;
  hw.x=hipack(v0.x,v0.y); hw.y=hipack(v0.z,v0.w); hw.z=hipack(v1.x,v1.y); hw.w=hipack(v1.z,v1.w);
  lw.x=lopack(v0.x,v0.y); lw.y=lopack(v0.z,v0.w); lw.z=lopack(v1.x,v1.y); lw.w=lopack(v1.z,v1.w);
  *(uint4v*)hi = hw; *(uint4v*)lo = lw;
}
// pack 8 f32 (from float4 pair) into hi/lo bf16x8 fragments
#define MK8(v0, v1, HI, LO) do { \
  (HI).u.x = hipack((v0).x,(v0).y); (HI).u.y = hipack((v0).z,(v0).w); \
  (HI).u.z = hipack((v1).x,(v1).y); (HI).u.w = hipack((v1).z,(v1).w); \
  (LO).u.x = lopack((v0).x,(v0).y); (LO).u.y = lopack((v0).z,(v0).w); \
  (LO).u.z = lopack((v1).x,(v1).y); (LO).u.w = lopack((v1).z,(v1).w); \
} while(0)

// Build B-fragments (sets 0 and 1) from a 32x32 D-layout register file `uu`
// using a cross-half shfl: lane (c32,h) reg r holds M[(r&3)+8*(r>>2)+4*h][c32].
// Output: B[k][c32] fragments, set0 k=0..15, set1 k=16..31, split hi/lo.
// For SYMMETRIC M this is also the A-operand row fragment of row c32.
#define DLAYOUT_TO_BFRAG(uu, h, B_H0, B_L0, B_H1, B_L1) do { \
  float sw_[16]; \
  _Pragma("unroll") \
  for (int r_=0;r_<16;++r_) sw_[r_] = __shfl_xor((uu)[r_], 32); \
  float v0_[8], v1_[8]; \
  v0_[0]=(h)? sw_[4] :(uu)[0];  v0_[1]=(h)? sw_[5] :(uu)[1]; \
  v0_[2]=(h)? sw_[6] :(uu)[2];  v0_[3]=(h)? sw_[7] :(uu)[3]; \
  v0_[4]=(h)? (uu)[4]:sw_[0];   v0_[5]=(h)? (uu)[5]:sw_[1]; \
  v0_[6]=(h)? (uu)[6]:sw_[2];   v0_[7]=(h)? (uu)[7]:sw_[3]; \
  v1_[0]=(h)? sw_[12]:(uu)[8];  v1_[1]=(h)? sw_[13]:(uu)[9]; \
  v1_[2]=(h)? sw_[14]:(uu)[10]; v1_[3]=(h)? sw_[15]:(uu)[11]; \
  v1_[4]=(h)? (uu)[12]:sw_[8];  v1_[5]=(h)? (uu)[13]:sw_[9]; \
  v1_[6]=(h)? (uu)[14]:sw_[10]; v1_[7]=(h)? (uu)[15]:sw_[11]; \
  (B_H0).u.x=hipack(v0_[0],v0_[1]); (B_H0).u.y=hipack(v0_[2],v0_[3]); \
  (B_H0).u.z=hipack(v0_[4],v0_[5]); (B_H0).u.w=hipack(v0_[6],v0_[7]); \
  (B_L0).u.x=lopack(v0_[0],v0_[1]); (B_L0).u.y=lopack(v0_[2],v0_[3]); \
  (B_L0).u.z=lopack(v0_[4],v0_[5]); (B_L0).u.w=lopack(v0_[6],v0_[7]); \
  (B_H1).u.x=hipack(v1_[0],v1_[1]); (B_H1).u.y=hipack(v1_[2],v1_[3]); \
  (B_H1).u.z=hipack(v1_[4],v1_[5]); (B_H1).u.w=hipack(v1_[6],v1_[7]); \
  (B_L1).u.x=lopack(v1_[0],v1_[1]); (B_L1).u.y=lopack(v1_[2],v1_[3]); \
  (B_L1).u.z=lopack(v1_[4],v1_[5]); (B_L1).u.w=lopack(v1_[6],v1_[7]); \
} while(0)

// ===== Forward Kalman filter: 1 wave/batch, MFMA bf16-split matmuls (unchanged R8) =====
__global__ __launch_bounds__(64) void kf_forward(
    const float* __restrict__ Yg, const float* __restrict__ Ug,
    const float* __restrict__ Ag, const float* __restrict__ Bg,
    const float* __restrict__ Cg, const float* __restrict__ mu0g,
    const float* __restrict__ Sig0g,
    float* __restrict__ outg, float* __restrict__ wsSig, float* __restrict__ wsMu)
{
  const int l   = threadIdx.x;
  const int b   = blockIdx.x;
  const int c32 = l & 31;
  const int h   = l >> 5;
  const int c16 = l & 15;
  const int q4  = l >> 4;
  const int kofA = h * 8;
  const int kofC = q4 * 8;
  const int rA = l >> 1, cA = (l & 1) << 4;
  const int rC = l >> 2, cC = (l & 3) << 3;

  __shared__ __align__(16) unsigned short Ahi[32][40], Alo[32][40];
  __shared__ __align__(16) unsigned short Chi[16][40], Clo[16][40];
  __shared__ __align__(16) unsigned short Ghi[32][40], Glo[32][40];
  __shared__ __align__(16) unsigned short Phi[32][40], Plo[32][40];
  __shared__ __align__(16) unsigned short Yhi[32][24], Ylo[32][24];
  __shared__ __align__(16) unsigned int   ZP[16][40];
  __shared__ __align__(16) unsigned int   KtTP[32][26];
  __shared__ __align__(16) float SLf[16][20];
  __shared__ __align__(16) float CSf[16][40];
  __shared__ __align__(16) float Bm[32][12];
  __shared__ __align__(16) float muf[32], mupf[32], rvf[16], yvf[16], uvf[8];

  const size_t bt0 = (size_t)b * TT;

  {
    const float* ap = Ag + bt0*1024 + rA*32 + cA;
    split16(*(const float4*)(ap+0), *(const float4*)(ap+4),
            *(const float4*)(ap+8), *(const float4*)(ap+12),
            &Ahi[rA][cA], &Alo[rA][cA]);
    const float* sp0 = Sig0g + rA*32 + cA;
    split16(*(const float4*)(sp0+0), *(const float4*)(sp0+4),
            *(const float4*)(sp0+8), *(const float4*)(sp0+12),
            &Ghi[rA][cA], &Glo[rA][cA]);
    const float* cp = Cg + bt0*512 + rC*32 + cC;
    split8(*(const float4*)(cp+0), *(const float4*)(cp+4),
           &Chi[rC][cC], &Clo[rC][cC]);
    *(float4*)&Bm[l>>1][(l&1)*4] = *(const float4*)(Bg + bt0*256 + (l>>1)*8 + (l&1)*4);
    if (l < 32) muf[l] = mu0g[l];
    if (l < 16) yvf[l] = Yg[bt0*16 + l];
    if (l < 8)  uvf[l] = Ug[bt0*8 + l];
  }

  for (int t = 0; t < TT; ++t) {
    const size_t bt = bt0 + t;

    // ---- P1': U = Sigma * A^T  (D-layout kept in registers) ----
    U8 a_h0, a_h1, a_l0, a_l1, s_h0, s_h1, s_l0, s_l1;
    a_h0.u = *(const uint4v*)&Ahi[c32][0  + kofA];
    a_h1.u = *(const uint4v*)&Ahi[c32][16 + kofA];
    a_l0.u = *(const uint4v*)&Alo[c32][0  + kofA];
    a_l1.u = *(const uint4v*)&Alo[c32][16 + kofA];
    s_h0.u = *(const uint4v*)&Ghi[c32][0  + kofA];
    s_h1.u = *(const uint4v*)&Ghi[c32][16 + kofA];
    s_l0.u = *(const uint4v*)&Glo[c32][0  + kofA];
    s_l1.u = *(const uint4v*)&Glo[c32][16 + kofA];
    f32x16 t1a, t1b;
    #pragma unroll
    for (int r=0;r<16;++r){ t1a[r] = 0.f; t1b[r] = 0.f; }
    t1a = mfma32(s_h0.b, a_h0.b, t1a);
    t1a = mfma32(s_h0.b, a_l0.b, t1a);
    t1a = mfma32(s_l0.b, a_h0.b, t1a);
    t1b = mfma32(s_h1.b, a_h1.b, t1b);
    t1b = mfma32(s_h1.b, a_l1.b, t1b);
    t1b = mfma32(s_l1.b, a_h1.b, t1b);
    float uu[16];
    #pragma unroll
    for (int r=0;r<16;++r) uu[r] = t1a[r] + t1b[r];
    // mu_p = A*mu + B*u
    float part = 0.f;
    {
      float4 m0 = *(const float4*)&muf[kofA];
      float4 m1 = *(const float4*)&muf[kofA+4];
      float4 m2 = *(const float4*)&muf[16+kofA];
      float4 m3 = *(const float4*)&muf[16+kofA+4];
      part = fmaf(blof(a_h0.u.x,a_l0.u.x), m0.x, part);
      part = fmaf(bhif(a_h0.u.x,a_l0.u.x), m0.y, part);
      part = fmaf(blof(a_h0.u.y,a_l0.u.y), m0.z, part);
      part = fmaf(bhif(a_h0.u.y,a_l0.u.y), m0.w, part);
      part = fmaf(blof(a_h0.u.z,a_l0.u.z), m1.x, part);
      part = fmaf(bhif(a_h0.u.z,a_l0.u.z), m1.y, part);
      part = fmaf(blof(a_h0.u.w,a_l0.u.w), m1.z, part);
      part = fmaf(bhif(a_h0.u.w,a_l0.u.w), m1.w, part);
      part = fmaf(blof(a_h1.u.x,a_l1.u.x), m2.x, part);
      part = fmaf(bhif(a_h1.u.x,a_l1.u.x), m2.y, part);
      part = fmaf(blof(a_h1.u.y,a_l1.u.y), m2.z, part);
      part = fmaf(bhif(a_h1.u.y,a_l1.u.y), m2.w, part);
      part = fmaf(blof(a_h1.u.z,a_l1.u.z), m3.x, part);
      part = fmaf(bhif(a_h1.u.z,a_l1.u.z), m3.y, part);
      part = fmaf(blof(a_h1.u.w,a_l1.u.w), m3.z, part);
      part = fmaf(bhif(a_h1.u.w,a_l1.u.w), m3.w, part);
    }
    part += __shfl_xor(part, 32);
    {
      float4 b0 = *(const float4*)&Bm[c32][0];
      float4 b1 = *(const float4*)&Bm[c32][4];
      float4 u0 = *(const float4*)&uvf[0];
      float4 u1 = *(const float4*)&uvf[4];
      part = fmaf(b0.x,u0.x, fmaf(b0.y,u0.y, fmaf(b0.z,u0.z, fmaf(b0.w,u0.w, part))));
      part = fmaf(b1.x,u1.x, fmaf(b1.y,u1.y, fmaf(b1.z,u1.z, fmaf(b1.w,u1.w, part))));
    }
    if (l < 32){ mupf[c32] = part; wsMu[bt*32 + c32] = part; }

    // ---- P2': Sigma_p = A * U + Q  (B-frags of U built in-register) ----
    U8 b_h0, b_h1, b_l0, b_l1;
    DLAYOUT_TO_BFRAG(uu, h, b_h0, b_l0, b_h1, b_l1);
    f32x16 spa, spb;
    #pragma unroll
    for (int r=0;r<16;++r){ spa[r] = 0.f; spb[r] = 0.f; }
    spa = mfma32(a_h0.b, b_h0.b, spa);
    spa = mfma32(a_h0.b, b_l0.b, spa);
    spa = mfma32(a_l0.b, b_h0.b, spa);
    spb = mfma32(a_h1.b, b_h1.b, spb);
    spb = mfma32(a_h1.b, b_l1.b, spb);
    spb = mfma32(a_l1.b, b_h1.b, spb);
    f32x16 sp;
    #pragma unroll
    for (int r=0;r<16;++r){
      int rr = (r&3) + 8*(r>>2) + 4*h;
      sp[r] = spa[r] + spb[r] + ((rr == c32) ? 0.01f : 0.f);
    }
    {
      float* wp = wsSig + (bt*32 + c32)*32;
      *(float4*)(wp + 0  + 4*h) = make_float4(sp[0], sp[1], sp[2], sp[3]);
      *(float4*)(wp + 8  + 4*h) = make_float4(sp[4], sp[5], sp[6], sp[7]);
      *(float4*)(wp + 16 + 4*h) = make_float4(sp[8], sp[9], sp[10],sp[11]);
      *(float4*)(wp + 24 + 4*h) = make_float4(sp[12],sp[13],sp[14],sp[15]);
      #pragma unroll
      for (int gq=0; gq<4; ++gq){
        uint2v hw, lw;
        hw.x = hipack(sp[4*gq+0], sp[4*gq+1]); hw.y = hipack(sp[4*gq+2], sp[4*gq+3]);
        lw.x = lopack(sp[4*gq+0], sp[4*gq+1]); lw.y = lopack(sp[4*gq+2], sp[4*gq+3]);
        *(uint2v*)&Phi[c32][8*gq + 4*h] = hw;
        *(uint2v*)&Plo[c32][8*gq + 4*h] = lw;
      }
    }

    // ---- P3: CS = C * Sigma_p ----
    U8 c_h, c_l, p_h0, p_l0, p_h1, p_l1;
    c_h.u  = *(const uint4v*)&Chi[c16][kofC];
    c_l.u  = *(const uint4v*)&Clo[c16][kofC];
    p_h0.u = *(const uint4v*)&Phi[c16][kofC];
    p_l0.u = *(const uint4v*)&Plo[c16][kofC];
    p_h1.u = *(const uint4v*)&Phi[16+c16][kofC];
    p_l1.u = *(const uint4v*)&Plo[16+c16][kofC];
    f32x4 cs0, cs1;
    #pragma unroll
    for (int r=0;r<4;++r){ cs0[r]=0.f; cs1[r]=0.f; }
    cs0 = mfma16(c_h.b, p_h0.b, cs0);
    cs0 = mfma16(c_h.b, p_l0.b, cs0);
    cs0 = mfma16(c_l.b, p_h0.b, cs0);
    cs1 = mfma16(c_h.b, p_h1.b, cs1);
    cs1 = mfma16(c_h.b, p_l1.b, cs1);
    cs1 = mfma16(c_l.b, p_h1.b, cs1);
    #pragma unroll
    for (int r=0;r<4;++r){
      int rr = q4*4 + r;
      ZP[rr][c16]     = packhl(cs0[r]);
      ZP[rr][16+c16]  = packhl(cs1[r]);
      CSf[rr][c16]    = cs0[r];
      CSf[rr][16+c16] = cs1[r];
    }
    {
      uint2v hw0, lw0, hw1, lw1;
      hw0.x = hipack(cs0[0],cs0[1]); hw0.y = hipack(cs0[2],cs0[3]);
      lw0.x = lopack(cs0[0],cs0[1]); lw0.y = lopack(cs0[2],cs0[3]);
      hw1.x = hipack(cs1[0],cs1[1]); hw1.y = hipack(cs1[2],cs1[3]);
      lw1.x = lopack(cs1[0],cs1[1]); lw1.y = lopack(cs1[2],cs1[3]);
      *(uint2v*)&Yhi[c16][q4*4]    = hw0; *(uint2v*)&Ylo[c16][q4*4]    = lw0;
      *(uint2v*)&Yhi[16+c16][q4*4] = hw1; *(uint2v*)&Ylo[16+c16][q4*4] = lw1;
    }
    // r = y - C*mu_p
    {
      float prr = 0.f;
      float4 m0 = *(const float4*)&mupf[kofC];
      float4 m1 = *(const float4*)&mupf[kofC+4];
      prr = fmaf(blof(c_h.u.x,c_l.u.x), m0.x, prr);
      prr = fmaf(bhif(c_h.u.x,c_l.u.x), m0.y, prr);
      prr = fmaf(blof(c_h.u.y,c_l.u.y), m0.z, prr);
      prr = fmaf(bhif(c_h.u.y,c_l.u.y), m0.w, prr);
      prr = fmaf(blof(c_h.u.z,c_l.u.z), m1.x, prr);
      prr = fmaf(bhif(c_h.u.z,c_l.u.z), m1.y, prr);
      prr = fmaf(blof(c_h.u.w,c_l.u.w), m1.z, prr);
      prr = fmaf(bhif(c_h.u.w,c_l.u.w), m1.w, prr);
      prr += __shfl_xor(prr, 16);
      prr += __shfl_xor(prr, 32);
      if (l < 16) rvf[l] = yvf[l] - prr;
    }

    // ---- P4: S = CS * C^T + R ----
    {
      U8 z_h, z_l;
      uint4v pz0 = *(const uint4v*)&ZP[c16][kofC];
      uint4v pz1 = *(const uint4v*)&ZP[c16][kofC+4];
      z_h.u = frag_hi(pz0, pz1); z_l.u = frag_lo(pz0, pz1);
      f32x4 ss;
      #pragma unroll
      for (int r=0;r<4;++r) ss[r] = 0.f;
      ss = mfma16(z_h.b, c_h.b, ss);
      ss = mfma16(z_h.b, c_l.b, ss);
      ss = mfma16(z_l.b, c_h.b, ss);
      #pragma unroll
      for (int r=0;r<4;++r){
        int rr = q4*4 + r;
        SLf[rr][c16] = ss[r] + ((rr == c16) ? 0.01f : 0.f);
      }
    }

    // ---- prefetch next-step inputs ----
    float4 pa0, pa1, pa2, pa3, pc0, pc1, pbv;
    float py = 0.f, pu = 0.f;
    pa0=pa1=pa2=pa3=make_float4(0.f,0.f,0.f,0.f);
    pc0=pc1=pbv=make_float4(0.f,0.f,0.f,0.f);
    if (t + 1 < TT){
      const float* ap = Ag + (bt+1)*1024 + rA*32 + cA;
      pa0 = *(const float4*)(ap+0);  pa1 = *(const float4*)(ap+4);
      pa2 = *(const float4*)(ap+8);  pa3 = *(const float4*)(ap+12);
      const float* cp = Cg + (bt+1)*512 + rC*32 + cC;
      pc0 = *(const float4*)(cp+0);  pc1 = *(const float4*)(cp+4);
      pbv = *(const float4*)(Bg + (bt+1)*256 + (l>>1)*8 + (l&1)*4);
      if (l < 16) py = Yg[(bt+1)*16 + l];
      if (l < 8)  pu = Ug[(bt+1)*8 + l];
    }

    // ---- P5: column-layout Gauss-Jordan via readlane (no shuffles) ----
    {
      float aug[16];
      if (l < 16){
        #pragma unroll
        for (int i=0;i<16;++i) aug[i] = 0.5f*(SLf[i][l] + SLf[l][i]);
      } else if (l < 48){
        #pragma unroll
        for (int i=0;i<16;++i) aug[i] = CSf[i][l-16];
      } else {
        #pragma unroll
        for (int i=0;i<16;++i) aug[i] = 0.f;
      }
      #pragma unroll
      for (int k=0;k<16;++k){
        float piv = rdl(aug[k], k);
        float q = -aug[k] * frcp(piv);
        #pragma unroll
        for (int i=0;i<16;++i){
          if (i == k) continue;
          float s = rdl(aug[i], k);
          aug[i] = fmaf(q, s, aug[i]);
        }
      }
      if (l >= 16 && l < 48){
        #pragma unroll
        for (int i=0;i<16;++i){
          float d = rdl(aug[i], i);
          KtTP[l-16][i] = packhl(-aug[i] * frcp(d));
        }
      }
    }

    // ---- P6: Sigma_f = Sigma_p - CS^T * Kt ----
    f32x16 sf = sp;
    {
      U8 y_h, y_l, kt_h, kt_l;
      y_h.u = *(const uint4v*)&Yhi[c32][8*h];
      y_l.u = *(const uint4v*)&Ylo[c32][8*h];
      uint4v k0, k1;
      { uint2v a0 = *(const uint2v*)&KtTP[c32][8*h];
        uint2v a1 = *(const uint2v*)&KtTP[c32][8*h+2];
        uint2v a2 = *(const uint2v*)&KtTP[c32][8*h+4];
        uint2v a3 = *(const uint2v*)&KtTP[c32][8*h+6];
        k0.x=a0.x; k0.y=a0.y; k0.z=a1.x; k0.w=a1.y;
        k1.x=a2.x; k1.y=a2.y; k1.z=a3.x; k1.w=a3.y; }
      kt_h.u = frag_hi(k0, k1); kt_l.u = frag_lo(k0, k1);
      sf = mfma32(y_h.b, kt_h.b, sf);
      sf = mfma32(y_h.b, kt_l.b, sf);
      sf = mfma32(y_l.b, kt_h.b, sf);
    }
    #pragma unroll
    for (int gq=0; gq<4; ++gq){
      uint2v hw, lw;
      hw.x = hipack(sf[4*gq+0], sf[4*gq+1]); hw.y = hipack(sf[4*gq+2], sf[4*gq+3]);
      lw.x = lopack(sf[4*gq+0], sf[4*gq+1]); lw.y = lopack(sf[4*gq+2], sf[4*gq+3]);
      *(uint2v*)&Ghi[c32][8*gq + 4*h] = hw;
      *(uint2v*)&Glo[c32][8*gq + 4*h] = lw;
    }
    {
      float* ob = outg + (bt*32)*33;
      #pragma unroll
      for (int r=0;r<16;++r){
        int rr = (r&3) + 8*(r>>2) + 4*h;
        ob[rr*33 + 1 + c32] = sf[r];
      }
      float mf = mupf[c32];
      #pragma unroll
      for (int p=0;p<16;++p){
        unsigned int w = KtTP[c32][p];
        mf = fmaf(-unpk(w), rvf[p], mf);
      }
      if (l < 32){ muf[c32] = mf; ob[c32*33] = mf; }
    }

    // ---- P7: stage next-step inputs ----
    if (t + 1 < TT){
      split16(pa0, pa1, pa2, pa3, &Ahi[rA][cA], &Alo[rA][cA]);
      split8(pc0, pc1, &Chi[rC][cC], &Clo[rC][cC]);
      *(float4*)&Bm[l>>1][(l&1)*4] = pbv;
      if (l < 16) yvf[l] = py;
      if (l < 8)  uvf[l] = pu;
    }
  }
}

// ===== Smoother precompute: 1 WAVE per (b,t), readlane-GJ inversion, MFMA (unchanged R8) =====
__global__ __launch_bounds__(64) void kf_precomp(
    const float* __restrict__ Ag, float* __restrict__ outg,
    float* __restrict__ wsSig, const float* __restrict__ wsMu)
{
  const int t = blockIdx.x;        // 0..126
  const int b = blockIdx.y;
  const int l = threadIdx.x;
  const int c32 = l & 31;
  const int h = l >> 5;
  const int kofA = h * 8;

  __shared__ __align__(16) float        Sffr[1060];
  __shared__ __align__(16) unsigned int MmP[32][34];
  __shared__ __align__(16) unsigned int VPT[32][34];
  __shared__ __align__(16) unsigned int JP [32][34];
  __shared__ float mp1f[32];

  const size_t bt = (size_t)b*TT + t;
  float* osl = outg + bt*1056;

  {
    const float4* src = (const float4*)osl;
    #pragma unroll
    for (int q=0;q<4;++q) *(float4*)&Sffr[(l + 64*q)*4] = src[l + 64*q];
    if (l < 8) *(float4*)&Sffr[(l + 256)*4] = src[l + 256];
    if (l < 32) mp1f[l] = wsMu[(bt+1)*32 + l];
  }

  float aug[32];
  if (l < 32){
    const float* pp = wsSig + (bt+1)*1024 + (size_t)l*32;
    #pragma unroll
    for (int q=0;q<8;++q){
      float4 v = *(const float4*)(pp + 4*q);
      aug[4*q]=v.x; aug[4*q+1]=v.y; aug[4*q+2]=v.z; aug[4*q+3]=v.w;
    }
  } else {
    #pragma unroll
    for (int i=0;i<32;++i) aug[i] = (i == l-32) ? 1.f : 0.f;
  }

  U8 a_h0, a_l0, a_h1, a_l1;
  {
    const float* ap = Ag + bt*1024 + c32*32;
    float4 v0 = *(const float4*)(ap + kofA);
    float4 v1 = *(const float4*)(ap + kofA + 4);
    float4 v2 = *(const float4*)(ap + 16 + kofA);
    float4 v3 = *(const float4*)(ap + 16 + kofA + 4);
    MK8(v0, v1, a_h0, a_l0);
    MK8(v2, v3, a_h1, a_l1);
  }
  U8 s_h0, s_l0, s_h1, s_l1;
  {
    const float* rp = &Sffr[c32*33 + 1];
    float4 v0, v1, v2, v3;
    v0.x=rp[kofA+0]; v0.y=rp[kofA+1]; v0.z=rp[kofA+2]; v0.w=rp[kofA+3];
    v1.x=rp[kofA+4]; v1.y=rp[kofA+5]; v1.z=rp[kofA+6]; v1.w=rp[kofA+7];
    v2.x=rp[16+kofA+0]; v2.y=rp[16+kofA+1]; v2.z=rp[16+kofA+2]; v2.w=rp[16+kofA+3];
    v3.x=rp[16+kofA+4]; v3.y=rp[16+kofA+5]; v3.z=rp[16+kofA+6]; v3.w=rp[16+kofA+7];
    MK8(v0, v1, s_h0, s_l0);
    MK8(v2, v3, s_h1, s_l1);
  }

  f32x16 ma, mb;
  #pragma unroll
  for (int r=0;r<16;++r){ ma[r]=0.f; mb[r]=0.f; }
  ma = mfma32(s_h0.b, a_h0.b, ma);
  ma = mfma32(s_h0.b, a_l0.b, ma);
  ma = mfma32(s_l0.b, a_h0.b, ma);
  mb = mfma32(s_h1.b, a_h1.b, mb);
  mb = mfma32(s_h1.b, a_l1.b, mb);
  mb = mfma32(s_l1.b, a_h1.b, mb);
  #pragma unroll
  for (int r=0;r<16;++r){
    int rr = (r&3) + 8*(r>>2) + 4*h;
    MmP[rr][c32] = packhl(ma[r] + mb[r]);
  }

  #pragma unroll
  for (int k=0;k<32;++k){
    float piv = rdl(aug[k], k);
    float q = -aug[k] * frcp(piv);
    #pragma unroll
    for (int i=0;i<32;++i){
      if (i == k) continue;
      float s = rdl(aug[i], k);
      aug[i] = fmaf(q, s, aug[i]);
    }
  }
  if (l >= 32){
    #pragma unroll
    for (int i=0;i<32;++i){
      float d = rdl(aug[i], i);
      VPT[l-32][i] = packhl(aug[i] * frcp(d));
    }
  }

  U8 m_h0, m_l0, m_h1, m_l1;
  {
    uint4v ua, ub, uc, ud;
    ua.x=MmP[c32][kofA+0]; ua.y=MmP[c32][kofA+1]; ua.z=MmP[c32][kofA+2]; ua.w=MmP[c32][kofA+3];
    ub.x=MmP[c32][kofA+4]; ub.y=MmP[c32][kofA+5]; ub.z=MmP[c32][kofA+6]; ub.w=MmP[c32][kofA+7];
    uc.x=MmP[c32][16+kofA+0]; uc.y=MmP[c32][16+kofA+1]; uc.z=MmP[c32][16+kofA+2]; uc.w=MmP[c32][16+kofA+3];
    ud.x=MmP[c32][16+kofA+4]; ud.y=MmP[c32][16+kofA+5]; ud.z=MmP[c32][16+kofA+6]; ud.w=MmP[c32][16+kofA+7];
    m_h0.u = frag_hi(ua, ub); m_l0.u = frag_lo(ua, ub);
    m_h1.u = frag_hi(uc, ud); m_l1.u = frag_lo(uc, ud);
  }
  U8 v_h0, v_l0, v_h1, v_l1;
  {
    uint4v ua, ub, uc, ud;
    ua.x=VPT[c32][kofA+0]; ua.y=VPT[c32][kofA+1]; ua.z=VPT[c32][kofA+2]; ua.w=VPT[c32][kofA+3];
    ub.x=VPT[c32][kofA+4]; ub.y=VPT[c32][kofA+5]; ub.z=VPT[c32][kofA+6]; ub.w=VPT[c32][kofA+7];
    uc.x=VPT[c32][16+kofA+0]; uc.y=VPT[c32][16+kofA+1]; uc.z=VPT[c32][16+kofA+2]; uc.w=VPT[c32][16+kofA+3];
    ud.x=VPT[c32][16+kofA+4]; ud.y=VPT[c32][16+kofA+5]; ud.z=VPT[c32][16+kofA+6]; ud.w=VPT[c32][16+kofA+7];
    v_h0.u = frag_hi(ua, ub); v_l0.u = frag_lo(ua, ub);
    v_h1.u = frag_hi(uc, ud); v_l1.u = frag_lo(uc, ud);
  }
  f32x16 ja, jb;
  #pragma unroll
  for (int r=0;r<16;++r){ ja[r]=0.f; jb[r]=0.f; }
  ja = mfma32(m_h0.b, v_h0.b, ja);
  ja = mfma32(m_h0.b, v_l0.b, ja);
  ja = mfma32(m_l0.b, v_h0.b, ja);
  jb = mfma32(m_h1.b, v_h1.b, jb);
  jb = mfma32(m_h1.b, v_l1.b, jb);
  jb = mfma32(m_l1.b, v_h1.b, jb);
  {
    float* jws = wsSig + (bt+1)*1024;
    #pragma unroll
    for (int r=0;r<16;++r){
      int rr = (r&3) + 8*(r>>2) + 4*h;
      float jv = ja[r] + jb[r];
      jws[rr*32 + c32] = jv;
      JP[rr][c32] = packhl(-jv);
    }
  }

  U8 nj_h0, nj_l0, nj_h1, nj_l1;
  {
    uint4v ua, ub, uc, ud;
    ua.x=JP[c32][kofA+0]; ua.y=JP[c32][kofA+1]; ua.z=JP[c32][kofA+2]; ua.w=JP[c32][kofA+3];
    ub.x=JP[c32][kofA+4]; ub.y=JP[c32][kofA+5]; ub.z=JP[c32][kofA+6]; ub.w=JP[c32][kofA+7];
    uc.x=JP[c32][16+kofA+0]; uc.y=JP[c32][16+kofA+1]; uc.z=JP[c32][16+kofA+2]; uc.w=JP[c32][16+kofA+3];
    ud.x=JP[c32][16+kofA+4]; ud.y=JP[c32][16+kofA+5]; ud.z=JP[c32][16+kofA+6]; ud.w=JP[c32][16+kofA+7];
    nj_h0.u = frag_hi(ua, ub); nj_l0.u = frag_lo(ua, ub);
    nj_h1.u = frag_hi(uc, ud); nj_l1.u = frag_lo(uc, ud);
  }
  f32x16 ea, eb;
  #pragma unroll
  for (int r=0;r<16;++r){
    int rr = (r&3) + 8*(r>>2) + 4*h;
    ea[r] = Sffr[rr*33 + 1 + c32];
    eb[r] = 0.f;
  }
  ea = mfma32(m_h0.b, nj_h0.b, ea);
  ea = mfma32(m_h0.b, nj_l0.b, ea);
  ea = mfma32(m_l0.b, nj_h0.b, ea);
  eb = mfma32(m_h1.b, nj_h1.b, eb);
  eb = mfma32(m_h1.b, nj_l1.b, eb);
  eb = mfma32(m_l1.b, nj_h1.b, eb);
  #pragma unroll
  for (int r=0;r<16;++r){
    int rr = (r&3) + 8*(r>>2) + 4*h;
    osl[rr*33 + 1 + c32] = ea[r] + eb[r];
  }

  {
    float e2 = Sffr[c32*33];
    #pragma unroll
    for (int k=0;k<32;++k)
      e2 = fmaf(unpk(JP[c32][k]), mp1f[k], e2);
    if (l < 32) osl[c32*33] = e2;
  }
}

// ===== Backward smoother: 1 WAVE per batch, Sigma_s register-resident (no SP LDS) =====
__global__ __launch_bounds__(64) void kf_backward(
    float* __restrict__ outg, const float* __restrict__ wsSig)
{
  const int l   = threadIdx.x;
  const int b   = blockIdx.x;
  const int c32 = l & 31;
  const int h   = l >> 5;
  const int kofA = h * 8;
  const int rA = l >> 1, cA = (l & 1) << 4;

  __shared__ __align__(16) unsigned short Jhi[32][40], Jlo[32][40];
  __shared__ float muv[32];

  const size_t base = (size_t)b * TT;

  float ss[16];     // Sigma_s in D-layout: ss[r] = Sig_s[rr][c32]
  float er[16]; float ev;
  {
    const float* os = outg + (base + TT - 1)*1056;
    #pragma unroll
    for (int r=0;r<16;++r){
      int rr = (r&3) + 8*(r>>2) + 4*h;
      ss[r] = os[rr*33 + 1 + c32];
    }
    if (l < 32) muv[l] = os[l*33];
    const float* jp = wsSig + ((base + TT - 1)*32 + rA)*32 + cA;
    split16(*(const float4*)(jp+0), *(const float4*)(jp+4),
            *(const float4*)(jp+8), *(const float4*)(jp+12),
            &Jhi[rA][cA], &Jlo[rA][cA]);
    const float* oe = outg + (base + TT - 2)*1056;
    #pragma unroll
    for (int r=0;r<16;++r){
      int rr = (r&3) + 8*(r>>2) + 4*h;
      er[r] = oe[rr*33 + 1 + c32];
    }
    ev = (l < 32) ? oe[l*33] : 0.f;
  }

  for (int t = TT - 2; t >= 0; --t) {
    float4 pj0, pj1, pj2, pj3; float ner[16]; float nev = 0.f;
    if (t > 0) {
      const float* jp = wsSig + ((base + t)*32 + rA)*32 + cA;
      pj0 = *(const float4*)(jp+0);  pj1 = *(const float4*)(jp+4);
      pj2 = *(const float4*)(jp+8);  pj3 = *(const float4*)(jp+12);
      const float* oe = outg + (base + t - 1)*1056;
      #pragma unroll
      for (int r=0;r<16;++r){
        int rr = (r&3) + 8*(r>>2) + 4*h;
        ner[r] = oe[rr*33 + 1 + c32];
      }
      if (l < 32) nev = oe[l*33];
    } else {
      pj0=pj1=pj2=pj3=make_float4(0.f,0.f,0.f,0.f);
      #pragma unroll
      for (int r=0;r<16;++r) ner[r] = 0.f;
    }

    // J fragments from LDS (rows)
    U8 a_h0, a_h1, a_l0, a_l1;
    a_h0.u = *(const uint4v*)&Jhi[c32][0  + kofA];
    a_h1.u = *(const uint4v*)&Jhi[c32][16 + kofA];
    a_l0.u = *(const uint4v*)&Jlo[c32][0  + kofA];
    a_l1.u = *(const uint4v*)&Jlo[c32][16 + kofA];
    // Sigma_s fragments from registers (symmetric: D-layout B-frag == row frag)
    U8 s_h0, s_l0, s_h1, s_l1;
    DLAYOUT_TO_BFRAG(ss, h, s_h0, s_l0, s_h1, s_l1);

    // W' = Sigma_s * J^T (split chains)
    f32x16 wa, wb;
    #pragma unroll
    for (int r=0;r<16;++r){ wa[r]=0.f; wb[r]=0.f; }
    wa = mfma32(s_h0.b, a_h0.b, wa);
    wa = mfma32(s_h0.b, a_l0.b, wa);
    wa = mfma32(s_l0.b, a_h0.b, wa);
    wb = mfma32(s_h1.b, a_h1.b, wb);
    wb = mfma32(s_h1.b, a_l1.b, wb);
    wb = mfma32(s_l1.b, a_h1.b, wb);
    float ww[16];
    #pragma unroll
    for (int r=0;r<16;++r) ww[r] = wa[r] + wb[r];

    // G = E + J * W'  (B-frags of W' built in-register)
    U8 bw_h0, bw_l0, bw_h1, bw_l1;
    DLAYOUT_TO_BFRAG(ww, h, bw_h0, bw_l0, bw_h1, bw_l1);
    f32x16 ga, gb;
    #pragma unroll
    for (int r=0;r<16;++r){ ga[r] = er[r]; gb[r] = 0.f; }
    ga = mfma32(a_h0.b, bw_h0.b, ga);
    ga = mfma32(a_h0.b, bw_l0.b, ga);
    ga = mfma32(a_l0.b, bw_h0.b, ga);
    gb = mfma32(a_h1.b, bw_h1.b, gb);
    gb = mfma32(a_h1.b, bw_l1.b, gb);
    gb = mfma32(a_l1.b, bw_h1.b, gb);

    // mu_s = e + J * mu_s
    float part = 0.f;
    {
      float4 m0 = *(const float4*)&muv[kofA];
      float4 m1 = *(const float4*)&muv[kofA+4];
      float4 m2 = *(const float4*)&muv[16+kofA];
      float4 m3 = *(const float4*)&muv[16+kofA+4];
      part = fmaf(blof(a_h0.u.x,a_l0.u.x), m0.x, part);
      part = fmaf(bhif(a_h0.u.x,a_l0.u.x), m0.y, part);
      part = fmaf(blof(a_h0.u.y,a_l0.u.y), m0.z, part);
      part = fmaf(bhif(a_h0.u.y,a_l0.u.y), m0.w, part);
      part = fmaf(blof(a_h0.u.z,a_l0.u.z), m1.x, part);
      part = fmaf(bhif(a_h0.u.z,a_l0.u.z), m1.y, part);
      part = fmaf(blof(a_h0.u.w,a_l0.u.w), m1.z, part);
      part = fmaf(bhif(a_h0.u.w,a_l0.u.w), m1.w, part);
      part = fmaf(blof(a_h1.u.x,a_l1.u.x), m2.x, part);
      part = fmaf(bhif(a_h1.u.x,a_l1.u.x), m2.y, part);
      part = fmaf(blof(a_h1.u.y,a_l1.u.y), m2.z, part);
      part = fmaf(bhif(a_h1.u.y,a_l1.u.y), m2.w, part);
      part = fmaf(blof(a_h1.u.z,a_l1.u.z), m3.x, part);
      part = fmaf(bhif(a_h1.u.z,a_l1.u.z), m3.y, part);
      part = fmaf(blof(a_h1.u.w,a_l1.u.w), m3.z, part);
      part = fmaf(bhif(a_h1.u.w,a_l1.u.w), m3.w, part);
    }
    part += __shfl_xor(part, 32);
    float mn = ev + part;

    {
      float* ob = outg + (base + t)*1056;
      #pragma unroll
      for (int r=0;r<16;++r){
        int rr = (r&3) + 8*(r>>2) + 4*h;
        float gv = ga[r] + gb[r];
        ob[rr*33 + 1 + c32] = gv;
        ss[r] = gv;                       // next Sigma_s, register-resident
      }
      if (l < 32){ muv[l] = mn; ob[l*33] = mn; }
    }

    if (t > 0){
      split16(pj0, pj1, pj2, pj3, &Jhi[rA][cA], &Jlo[rA][cA]);
      #pragma unroll
      for (int r=0;r<16;++r) er[r] = ner[r];
      ev = nev;
    }
  }
}

extern "C" void kernel_launch(void* const* d_in, const int* in_sizes, int n_in,
                              void* d_out, int out_size, void* d_ws, size_t ws_size,
                              hipStream_t stream) {
  (void)in_sizes; (void)n_in; (void)out_size; (void)ws_size;
  const float* Yg   = (const float*)d_in[0];
  const float* Ug   = (const float*)d_in[1];
  const float* Ag   = (const float*)d_in[2];
  const float* Bg   = (const float*)d_in[3];
  const float* Cg   = (const float*)d_in[4];
  const float* mu0g = (const float*)d_in[5];
  const float* S0g  = (const float*)d_in[6];
  float* outg = (float*)d_out;
  float* wsSig = (float*)d_ws;
  float* wsMu  = wsSig + (size_t)NB*TT*NSZ*NSZ;

  hipLaunchKernelGGL(kf_forward, dim3(NB), dim3(64), 0, stream,
                     Yg, Ug, Ag, Bg, Cg, mu0g, S0g, outg, wsSig, wsMu);
  hipLaunchKernelGGL(kf_precomp, dim3(TT-1, NB), dim3(64), 0, stream,
                     Ag, outg, wsSig, wsMu);
  hipLaunchKernelGGL(kf_backward, dim3(NB), dim3(64), 0, stream,
                     outg, wsSig);
}